// Round 5
// baseline (353.212 us; speedup 1.0000x reference)
//
#include <hip/hip_runtime.h>
#include <hip/hip_bf16.h>
#include <stdint.h>

typedef __bf16 bf16x8 __attribute__((ext_vector_type(8)));
typedef __bf16 bf16x4 __attribute__((ext_vector_type(4)));
typedef float  f32x4  __attribute__((ext_vector_type(4)));
typedef float  f32x2  __attribute__((ext_vector_type(2)));

#define MFMA16(a,b,c) __builtin_amdgcn_mfma_f32_16x16x32_bf16((a),(b),(c),0,0,0)

static constexpr int H_   = 256;
static constexpr int KEV  = 10;
static constexpr int NTOK = 32 * 4096;

// Pade(5,5) tanh: x*(945+105t+t^2)/(945+420t+15t^2), |err|<7e-4 with clamp. No transcendental.
__device__ __forceinline__ float ptanh(float x){
    float t = x * x;
    float n = fmaf(t, t + 105.0f, 945.0f);
    float d = fmaf(t, fmaf(t, 15.0f, 420.0f), 945.0f);
    float r = x * n * __builtin_amdgcn_rcpf(d);
    return fminf(1.0f, fmaxf(-1.0f, r));
}

__device__ __forceinline__ bf16x8 cvtFrag(const float* p){
    f32x4 a = *(const f32x4*)p;
    f32x4 b = *(const f32x4*)(p + 4);
    bf16x8 r;
    #pragma unroll
    for (int j = 0; j < 4; ++j){ r[j] = (__bf16)a[j]; r[4 + j] = (__bf16)b[j]; }
    return r;
}

// ---- prep 1: v1[j] = sum_k w2[j][256+k]*w1[k]; c1[j] = sum_k w2[j][256+k]*b1[k] + b2[j]
__global__ void prep_vc(const float* __restrict__ w1, const float* __restrict__ b1,
                        const float* __restrict__ w2, const float* __restrict__ b2,
                        float* __restrict__ vc){
    int j = blockIdx.x * 4 + (threadIdx.x >> 6);
    int l = threadIdx.x & 63;
    const float* row = w2 + (size_t)j * (2 * H_) + H_;
    float v = 0.f, cc = 0.f;
    #pragma unroll
    for (int i = 0; i < 4; ++i){
        int k = l + 64 * i;
        float w = row[k];
        v  += w * w1[k];
        cc += w * b1[k];
    }
    #pragma unroll
    for (int off = 32; off; off >>= 1){
        v  += __shfl_down(v,  off, 64);
        cc += __shfl_down(cc, off, 64);
    }
    if (l == 0){ vc[j] = v; vc[H_ + j] = cc + b2[j]; }
}

// ---- prep 2: pack weights to bf16 in MFMA fragment order.
// chunk b (layer b>>4, n0 = b&15): slot = (s*4+q)*16+c holds W[n0*16+c][32s+8q .. +8]
__global__ void prep_pack(const float* __restrict__ w2, const float* __restrict__ wA,
                          const float* __restrict__ wB, __hip_bfloat16* __restrict__ pk){
    int b  = blockIdx.x;
    int L  = b >> 4, n0 = b & 15;
    const float* W = (L == 0) ? w2 : ((L == 1) ? wA : wB);
    int K = (L == 0) ? 2 * H_ : H_;       // layer1 uses first 256 cols of w2
    __hip_bfloat16* dst = pk + (size_t)b * 4096;
    int t = threadIdx.x;
    #pragma unroll
    for (int u = 0; u < 2; ++u){
        int slot = t * 2 + u;
        int s = slot >> 6, q = (slot >> 4) & 3, c = slot & 15;
        const float* src = W + (size_t)(n0 * 16 + c) * K + 32 * s + 8 * q;
        #pragma unroll
        for (int j = 0; j < 8; ++j) dst[slot * 8 + j] = __float2bfloat16(src[j]);
    }
}

// Barrier-free fused network. 4 waves x 32 tokens = 128 tokens/block.
// Weights: global->VGPR double-buffered (L1/L2-hot packed fragments). Acts: wave-private LDS.
__global__ __launch_bounds__(256, 1) void chfn_kernel(
    const float* __restrict__ hs, const float* __restrict__ td,
    const __hip_bfloat16* __restrict__ wpk,
    const float* __restrict__ bA, const float* __restrict__ bB,
    const float* __restrict__ w3, const float* __restrict__ b3,
    const float* __restrict__ vc,
    float* __restrict__ out)
{
    extern __shared__ __hip_bfloat16 smem[];          // 128 KB dynamic
    __hip_bfloat16* sA = smem;                        // [128 tok][256] swizzled
    __hip_bfloat16* sD = smem + 128 * H_;

    const int tid  = threadIdx.x;
    const int wave = tid >> 6;
    const int lane = tid & 63;
    const int q    = lane >> 4;
    const int c    = lane & 15;
    const int tb   = blockIdx.x * 128 + wave * 32;    // groups t=0,1 -> tokens tb+16t+c
    const int baseRow = wave * 32;

    const bf16x8* wp = (const bf16x8*)wpk;            // fragment granularity
    const int ws = q * 16 + c;                        // lane slot within chunk

    // ---- prefetch weight chunk 0 into W0 (issue before anything else)
    bf16x8 W0[8], W1[8];
    {
        const bf16x8* b = wp + ws;
        #pragma unroll
        for (int s = 0; s < 8; ++s) W0[s] = b[s * 64];
    }

    // ---- h fragments, both token groups (fp32, one-time)
    bf16x8 aF0[8], aF1[8], aB0[8], aB1[8];
    {
        const float* h0 = hs + (size_t)(tb + c) * H_ + 8 * q;
        const float* h1 = hs + (size_t)(tb + 16 + c) * H_ + 8 * q;
        #pragma unroll
        for (int s = 0; s < 8; ++s){
            aF0[s] = cvtFrag(h0 + 32 * s);
            aF1[s] = cvtFrag(h1 + 32 * s);
        }
    }
    float td0 = td[tb + c];
    float td1 = td[tb + 16 + c];

    // ---- layer 1: x = h@w2h^T + td*v1 + c1; act = tanh(x); tangent = (1-act^2)*v1
    #pragma unroll 2
    for (int n0 = 0; n0 < 16; ++n0){
        bf16x8* cur = (n0 & 1) ? W1 : W0;
        bf16x8* nxt = (n0 & 1) ? W0 : W1;
        {   // prefetch chunk n0+1 (chunk 16 = first L2 chunk at n0=15)
            const bf16x8* b = wp + (size_t)(n0 + 1) * 512 + ws;
            #pragma unroll
            for (int s = 0; s < 8; ++s) nxt[s] = b[s * 64];
        }
        f32x4 v4 = *(const f32x4*)(vc + n0 * 16 + 4 * q);
        f32x4 c4 = *(const f32x4*)(vc + H_ + n0 * 16 + 4 * q);
        f32x4 fa0 = {0.f,0.f,0.f,0.f}, fb0 = {0.f,0.f,0.f,0.f};
        f32x4 fa1 = {0.f,0.f,0.f,0.f}, fb1 = {0.f,0.f,0.f,0.f};
        #pragma unroll
        for (int s = 0; s < 4; ++s){
            fa0 = MFMA16(cur[s],     aF0[s],     fa0);
            fa1 = MFMA16(cur[s],     aF1[s],     fa1);
            fb0 = MFMA16(cur[s + 4], aF0[s + 4], fb0);
            fb1 = MFMA16(cur[s + 4], aF1[s + 4], fb1);
        }
        #pragma unroll
        for (int t = 0; t < 2; ++t){
            const f32x4& fa = t ? fa1 : fa0;
            const f32x4& fb = t ? fb1 : fb0;
            float tdg = t ? td1 : td0;
            bf16x4 pa, pd;
            #pragma unroll
            for (int r = 0; r < 4; ++r){
                float x  = (fa[r] + fb[r]) + fmaf(tdg, v4[r], c4[r]);
                float th = ptanh(x);
                float dd = fmaf(-th, th, 1.0f) * v4[r];
                pa[r] = (__bf16)th; pd[r] = (__bf16)dd;
            }
            int off = (baseRow + 16 * t + c) * H_ +
                      (((2 * n0 + (q >> 1) + c) & 31) << 3) + ((q & 1) << 2);
            *(bf16x4*)((void*)(sA + off)) = pa;
            *(bf16x4*)((void*)(sD + off)) = pd;
        }
    }

    // ---- layers 2 & 3 (no barriers: acts are wave-private)
    #pragma unroll 1
    for (int L = 0; L < 2; ++L){
        const float* bias = L ? bB : bA;
        {   // reload act/tangent fragments for both groups
            const __hip_bfloat16* a0 = sA + (baseRow + c) * H_;
            const __hip_bfloat16* a1 = sA + (baseRow + 16 + c) * H_;
            const __hip_bfloat16* d0 = sD + (baseRow + c) * H_;
            const __hip_bfloat16* d1 = sD + (baseRow + 16 + c) * H_;
            #pragma unroll
            for (int s = 0; s < 8; ++s){
                int chn = (((4 * s + q) + c) & 31) << 3;
                aF0[s] = *(const bf16x8*)(a0 + chn);
                aF1[s] = *(const bf16x8*)(a1 + chn);
                aB0[s] = *(const bf16x8*)(d0 + chn);
                aB1[s] = *(const bf16x8*)(d1 + chn);
            }
        }
        #pragma unroll 2
        for (int n0 = 0; n0 < 16; ++n0){
            int g = 16 * (L + 1) + n0;
            bf16x8* cur = (n0 & 1) ? W1 : W0;
            bf16x8* nxt = (n0 & 1) ? W0 : W1;
            {
                int gn = g + 1; if (gn > 47) gn = 47;     // clamp: harmless reload at end
                const bf16x8* b = wp + (size_t)gn * 512 + ws;
                #pragma unroll
                for (int s = 0; s < 8; ++s) nxt[s] = b[s * 64];
            }
            f32x4 b4 = *(const f32x4*)(bias + n0 * 16 + 4 * q);
            f32x4 fa0 = {0.f,0.f,0.f,0.f}, fb0 = {0.f,0.f,0.f,0.f};
            f32x4 ga0 = {0.f,0.f,0.f,0.f}, gb0 = {0.f,0.f,0.f,0.f};
            f32x4 fa1 = {0.f,0.f,0.f,0.f}, fb1 = {0.f,0.f,0.f,0.f};
            f32x4 ga1 = {0.f,0.f,0.f,0.f}, gb1 = {0.f,0.f,0.f,0.f};
            #pragma unroll
            for (int s = 0; s < 4; ++s){
                fa0 = MFMA16(cur[s],     aF0[s],     fa0);
                ga0 = MFMA16(cur[s],     aB0[s],     ga0);
                fa1 = MFMA16(cur[s],     aF1[s],     fa1);
                ga1 = MFMA16(cur[s],     aB1[s],     ga1);
                fb0 = MFMA16(cur[s + 4], aF0[s + 4], fb0);
                gb0 = MFMA16(cur[s + 4], aB0[s + 4], gb0);
                fb1 = MFMA16(cur[s + 4], aF1[s + 4], fb1);
                gb1 = MFMA16(cur[s + 4], aB1[s + 4], gb1);
            }
            #pragma unroll
            for (int t = 0; t < 2; ++t){
                const f32x4& fa = t ? fa1 : fa0;  const f32x4& fb = t ? fb1 : fb0;
                const f32x4& ga = t ? ga1 : ga0;  const f32x4& gb = t ? gb1 : gb0;
                bf16x4 pa, pd;
                #pragma unroll
                for (int r = 0; r < 4; ++r){
                    float th = ptanh((fa[r] + fb[r]) + b4[r]);
                    float dd = fmaf(-th, th, 1.0f) * (ga[r] + gb[r]);
                    pa[r] = (__bf16)th; pd[r] = (__bf16)dd;
                }
                int off = (baseRow + 16 * t + c) * H_ +
                          (((2 * n0 + (q >> 1) + c) & 31) << 3) + ((q & 1) << 2);
                *(bf16x4*)((void*)(sA + off)) = pa;
                *(bf16x4*)((void*)(sD + off)) = pd;
            }
        }
    }

    // ---- head (K=10): rows = feats (valid <10), cols = tokens
    {
        const __hip_bfloat16* a0 = sA + (baseRow + c) * H_;
        const __hip_bfloat16* a1 = sA + (baseRow + 16 + c) * H_;
        const __hip_bfloat16* d0 = sD + (baseRow + c) * H_;
        const __hip_bfloat16* d1 = sD + (baseRow + 16 + c) * H_;
        #pragma unroll
        for (int s = 0; s < 8; ++s){
            int chn = (((4 * s + q) + c) & 31) << 3;
            aF0[s] = *(const bf16x8*)(a0 + chn);
            aF1[s] = *(const bf16x8*)(a1 + chn);
            aB0[s] = *(const bf16x8*)(d0 + chn);
            aB1[s] = *(const bf16x8*)(d1 + chn);
        }
        int crow = (c < KEV) ? c : 0;                  // A-row clamp; rows>=10 never stored
        const float* wp3 = w3 + (size_t)crow * H_ + 8 * q;
        bf16x8 w3f[8];
        #pragma unroll
        for (int s = 0; s < 8; ++s) w3f[s] = cvtFrag(wp3 + 32 * s);

        f32x4 fa0 = {0.f,0.f,0.f,0.f}, fb0 = {0.f,0.f,0.f,0.f};
        f32x4 ga0 = {0.f,0.f,0.f,0.f}, gb0 = {0.f,0.f,0.f,0.f};
        f32x4 fa1 = {0.f,0.f,0.f,0.f}, fb1 = {0.f,0.f,0.f,0.f};
        f32x4 ga1 = {0.f,0.f,0.f,0.f}, gb1 = {0.f,0.f,0.f,0.f};
        #pragma unroll
        for (int s = 0; s < 4; ++s){
            fa0 = MFMA16(w3f[s],     aF0[s],     fa0);
            ga0 = MFMA16(w3f[s],     aB0[s],     ga0);
            fa1 = MFMA16(w3f[s],     aF1[s],     fa1);
            ga1 = MFMA16(w3f[s],     aB1[s],     ga1);
            fb0 = MFMA16(w3f[s + 4], aF0[s + 4], fb0);
            gb0 = MFMA16(w3f[s + 4], aB0[s + 4], gb0);
            fb1 = MFMA16(w3f[s + 4], aF1[s + 4], fb1);
            gb1 = MFMA16(w3f[s + 4], aB1[s + 4], gb1);
        }
        int fbase = 4 * q;
        #pragma unroll
        for (int t = 0; t < 2; ++t){
            const f32x4& fa = t ? fa1 : fa0;  const f32x4& fb = t ? fb1 : fb0;
            const f32x4& ga = t ? ga1 : ga0;  const f32x4& gb = t ? gb1 : gb0;
            size_t token = tb + 16 * t + c;
            float sp[4], dv[4];
            #pragma unroll
            for (int r = 0; r < 4; ++r){
                int fi   = fbase + r;
                float bn = b3[(fi < KEV) ? fi : (KEV - 1)];
                float z  = (fa[r] + fb[r]) + bn;
                float a  = fabsf(z);
                float e  = __builtin_amdgcn_exp2f(-1.4426950408889634f * a);  // exp(-|z|)
                sp[r] = fmaxf(z, 0.f) + 0.69314718055994531f * __builtin_amdgcn_logf(1.0f + e);
                float sg = __builtin_amdgcn_rcpf(1.0f + e);
                sg = (z >= 0.f) ? sg : 1.0f - sg;                              // sigmoid(z)
                dv[r] = sg * (ga[r] + gb[r]) * (1.0f / 131072.0f);             // /(B*S)
            }
            float* o0 = out + token * KEV + fbase;
            float* o1 = out + (size_t)NTOK * KEV + token * KEV + fbase;
            if (q < 2){
                *(f32x2*)o0       = (f32x2){sp[0], sp[1]};
                *(f32x2*)(o0 + 2) = (f32x2){sp[2], sp[3]};
                *(f32x2*)o1       = (f32x2){dv[0], dv[1]};
                *(f32x2*)(o1 + 2) = (f32x2){dv[2], dv[3]};
            } else if (q == 2){
                *(f32x2*)o0 = (f32x2){sp[0], sp[1]};
                *(f32x2*)o1 = (f32x2){dv[0], dv[1]};
            }
        }
    }
}

extern "C" void kernel_launch(void* const* d_in, const int* in_sizes, int n_in,
                              void* d_out, int out_size, void* d_ws, size_t ws_size,
                              hipStream_t stream){
    const float* hs = (const float*)d_in[0];
    const float* td = (const float*)d_in[1];
    const float* w1 = (const float*)d_in[2];
    const float* b1 = (const float*)d_in[3];
    const float* w2 = (const float*)d_in[4];
    const float* b2 = (const float*)d_in[5];
    const float* wA = (const float*)d_in[6];
    const float* bA = (const float*)d_in[7];
    const float* wB = (const float*)d_in[8];
    const float* bB = (const float*)d_in[9];
    const float* w3 = (const float*)d_in[10];
    const float* b3 = (const float*)d_in[11];

    float*          vc  = (float*)d_ws;                              // 512 fp32
    __hip_bfloat16* wpk = (__hip_bfloat16*)((char*)d_ws + 4096);     // 48*8KB packed weights
    float*          outp = (float*)d_out;

    // allow 128 KB dynamic LDS (host-side attr set; idempotent, capture-safe)
    (void)hipFuncSetAttribute((const void*)chfn_kernel,
                              hipFuncAttributeMaxDynamicSharedMemorySize, 131072);

    prep_vc  <<<64, 256, 0, stream>>>(w1, b1, w2, b2, vc);
    prep_pack<<<48, 256, 0, stream>>>(w2, wA, wB, wpk);
    chfn_kernel<<<NTOK / 128, 256, 131072, stream>>>(hs, td, wpk, bA, bB, w3, b3, vc, outp);
}

// Round 6
// 330.623 us; speedup vs baseline: 1.0683x; 1.0683x over previous
//
#include <hip/hip_runtime.h>
#include <hip/hip_bf16.h>
#include <stdint.h>

typedef __bf16 bf16x8 __attribute__((ext_vector_type(8)));
typedef __bf16 bf16x4 __attribute__((ext_vector_type(4)));
typedef float  f32x4  __attribute__((ext_vector_type(4)));
typedef float  f32x2  __attribute__((ext_vector_type(2)));

#define MFMA16(a,b,c) __builtin_amdgcn_mfma_f32_16x16x32_bf16((a),(b),(c),0,0,0)

static constexpr int H_   = 256;
static constexpr int KEV  = 10;
static constexpr int NTOK = 32 * 4096;

// Pade(5,5) tanh: x*(945+105t+t^2)/(945+420t+15t^2), |err|<7e-4 with clamp.
__device__ __forceinline__ float ptanh(float x){
    float t = x * x;
    float n = fmaf(t, t + 105.0f, 945.0f);
    float d = fmaf(t, fmaf(t, 15.0f, 420.0f), 945.0f);
    float r = x * n * __builtin_amdgcn_rcpf(d);
    return fminf(1.0f, fmaxf(-1.0f, r));
}

__device__ __forceinline__ bf16x8 cvtFrag(const float* p){
    f32x4 a = *(const f32x4*)p;
    f32x4 b = *(const f32x4*)(p + 4);
    bf16x8 r;
    #pragma unroll
    for (int j = 0; j < 4; ++j){ r[j] = (__bf16)a[j]; r[4 + j] = (__bf16)b[j]; }
    return r;
}

// ---- prep 1: v1[j] = sum_k w2[j][256+k]*w1[k]; c1[j] = sum_k w2[j][256+k]*b1[k] + b2[j]
__global__ void prep_vc(const float* __restrict__ w1, const float* __restrict__ b1,
                        const float* __restrict__ w2, const float* __restrict__ b2,
                        float* __restrict__ vc){
    int j = blockIdx.x * 4 + (threadIdx.x >> 6);
    int l = threadIdx.x & 63;
    const float* row = w2 + (size_t)j * (2 * H_) + H_;
    float v = 0.f, cc = 0.f;
    #pragma unroll
    for (int i = 0; i < 4; ++i){
        int k = l + 64 * i;
        float w = row[k];
        v  += w * w1[k];
        cc += w * b1[k];
    }
    #pragma unroll
    for (int off = 32; off; off >>= 1){
        v  += __shfl_down(v,  off, 64);
        cc += __shfl_down(cc, off, 64);
    }
    if (l == 0){ vc[j] = v; vc[H_ + j] = cc + b2[j]; }
}

// ---- prep 2: pack weights to bf16 in MFMA fragment order.
// chunk b (layer b>>4, n0 = b&15): slot = (s*4+q)*16+c holds W[n0*16+c][32s+8q .. +8]
__global__ void prep_pack(const float* __restrict__ w2, const float* __restrict__ wA,
                          const float* __restrict__ wB, __hip_bfloat16* __restrict__ pk){
    int b  = blockIdx.x;
    int L  = b >> 4, n0 = b & 15;
    const float* W = (L == 0) ? w2 : ((L == 1) ? wA : wB);
    int K = (L == 0) ? 2 * H_ : H_;       // layer1 uses first 256 cols of w2
    __hip_bfloat16* dst = pk + (size_t)b * 4096;
    int t = threadIdx.x;
    #pragma unroll
    for (int u = 0; u < 2; ++u){
        int slot = t * 2 + u;
        int s = slot >> 6, q = (slot >> 4) & 3, c = slot & 15;
        const float* src = W + (size_t)(n0 * 16 + c) * K + 32 * s + 8 * q;
        #pragma unroll
        for (int j = 0; j < 8; ++j) dst[slot * 8 + j] = __float2bfloat16(src[j]);
    }
}

// Barrier-free fused network. 4 waves x 16 tokens; 64 KB LDS -> 2 blocks/CU (2 waves/SIMD).
// Weights: global->VGPR double-buffered (L1-hot packed fragments). Acts: wave-private LDS.
__global__ __launch_bounds__(256, 2) void chfn_kernel(
    const float* __restrict__ hs, const float* __restrict__ td,
    const __hip_bfloat16* __restrict__ wpk,
    const float* __restrict__ bA, const float* __restrict__ bB,
    const float* __restrict__ w3, const float* __restrict__ b3,
    const float* __restrict__ vc,
    float* __restrict__ out)
{
    __shared__ __hip_bfloat16 sA[4 * 16 * H_];     // 32 KB activations (swizzled)
    __shared__ __hip_bfloat16 sD[4 * 16 * H_];     // 32 KB tangents

    const int tid  = threadIdx.x;
    const int wave = tid >> 6;
    const int lane = tid & 63;
    const int q    = lane >> 4;
    const int c    = lane & 15;
    const int tb   = blockIdx.x * 64 + wave * 16;
    const int wrow = wave * 16;

    const bf16x8* wp = (const bf16x8*)wpk;
    const int ws = q * 16 + c;                     // lane slot within chunk

    // prefetch weight chunk 0
    bf16x8 W0[8], W1[8];
    {
        const bf16x8* b = wp + ws;
        #pragma unroll
        for (int s = 0; s < 8; ++s) W0[s] = b[s * 64];
    }

    // h fragments (fp32 -> bf16, one-time)
    bf16x8 aF[8], aB[8];
    {
        const float* h0 = hs + (size_t)(tb + c) * H_ + 8 * q;
        #pragma unroll
        for (int s = 0; s < 8; ++s) aF[s] = cvtFrag(h0 + 32 * s);
    }
    float myTd = td[tb + c];

    // ---- layer 1: x = h@w2h^T + td*v1 + c1; act = tanh(x); tangent = (1-act^2)*v1
    #pragma unroll 2
    for (int n0 = 0; n0 < 16; ++n0){
        bf16x8* cur = (n0 & 1) ? W1 : W0;
        bf16x8* nxt = (n0 & 1) ? W0 : W1;
        {   // prefetch chunk n0+1
            const bf16x8* b = wp + (size_t)(n0 + 1) * 512 + ws;
            #pragma unroll
            for (int s = 0; s < 8; ++s) nxt[s] = b[s * 64];
        }
        f32x4 v4 = *(const f32x4*)(vc + n0 * 16 + 4 * q);
        f32x4 c4 = *(const f32x4*)(vc + H_ + n0 * 16 + 4 * q);
        f32x4 fa = c4;                              // fold c1 into accumulator init
        f32x4 fb = {0.f,0.f,0.f,0.f};
        #pragma unroll
        for (int s = 0; s < 4; ++s){
            fa = MFMA16(cur[s],     aF[s],     fa);
            fb = MFMA16(cur[s + 4], aF[s + 4], fb);
        }
        bf16x4 pa, pd;
        #pragma unroll
        for (int r = 0; r < 4; ++r){
            float x  = fmaf(myTd, v4[r], fa[r] + fb[r]);
            float th = ptanh(x);
            float dd = fmaf(-th, th, 1.0f) * v4[r];
            pa[r] = (__bf16)th; pd[r] = (__bf16)dd;
        }
        int off = (wrow + c) * H_ + (((2 * n0 + (q >> 1) + c) & 31) << 3) + ((q & 1) << 2);
        *(bf16x4*)((void*)(sA + off)) = pa;
        *(bf16x4*)((void*)(sD + off)) = pd;
    }

    // ---- layers 2 & 3 (no barriers: acts are wave-private)
    #pragma unroll 1
    for (int L = 0; L < 2; ++L){
        const float* bias = L ? bB : bA;
        {   // reload act/tangent fragments
            const __hip_bfloat16* a0 = sA + (wrow + c) * H_;
            const __hip_bfloat16* d0 = sD + (wrow + c) * H_;
            #pragma unroll
            for (int s = 0; s < 8; ++s){
                int chn = (((4 * s + q) + c) & 31) << 3;
                aF[s] = *(const bf16x8*)(a0 + chn);
                aB[s] = *(const bf16x8*)(d0 + chn);
            }
        }
        #pragma unroll 2
        for (int n0 = 0; n0 < 16; ++n0){
            int g = 16 * (L + 1) + n0;
            bf16x8* cur = (n0 & 1) ? W1 : W0;
            bf16x8* nxt = (n0 & 1) ? W0 : W1;
            {
                int gn = g + 1; if (gn > 47) gn = 47;    // clamped end reload, harmless
                const bf16x8* b = wp + (size_t)gn * 512 + ws;
                #pragma unroll
                for (int s = 0; s < 8; ++s) nxt[s] = b[s * 64];
            }
            f32x4 b4 = *(const f32x4*)(bias + n0 * 16 + 4 * q);
            f32x4 fa = b4;                           // fold bias into accumulator init
            f32x4 fb = {0.f,0.f,0.f,0.f};
            f32x4 ga = {0.f,0.f,0.f,0.f};
            f32x4 gb = {0.f,0.f,0.f,0.f};
            #pragma unroll
            for (int s = 0; s < 4; ++s){
                fa = MFMA16(cur[s],     aF[s],     fa);
                ga = MFMA16(cur[s],     aB[s],     ga);
                fb = MFMA16(cur[s + 4], aF[s + 4], fb);
                gb = MFMA16(cur[s + 4], aB[s + 4], gb);
            }
            bf16x4 pa, pd;
            #pragma unroll
            for (int r = 0; r < 4; ++r){
                float th = ptanh(fa[r] + fb[r]);
                float dd = fmaf(-th, th, 1.0f) * (ga[r] + gb[r]);
                pa[r] = (__bf16)th; pd[r] = (__bf16)dd;
            }
            int off = (wrow + c) * H_ + (((2 * n0 + (q >> 1) + c) & 31) << 3) + ((q & 1) << 2);
            *(bf16x4*)((void*)(sA + off)) = pa;
            *(bf16x4*)((void*)(sD + off)) = pd;
        }
    }

    // ---- head (K=10): rows = feats 4q+r (valid <10), cols = tokens c
    {
        const __hip_bfloat16* a0 = sA + (wrow + c) * H_;
        const __hip_bfloat16* d0 = sD + (wrow + c) * H_;
        #pragma unroll
        for (int s = 0; s < 8; ++s){
            int chn = (((4 * s + q) + c) & 31) << 3;
            aF[s] = *(const bf16x8*)(a0 + chn);
            aB[s] = *(const bf16x8*)(d0 + chn);
        }
        int crow = (c < KEV) ? c : 0;               // A-row clamp; rows>=10 never stored
        const float* wp3 = w3 + (size_t)crow * H_ + 8 * q;
        f32x4 fa = {0.f,0.f,0.f,0.f}, fb = {0.f,0.f,0.f,0.f};
        f32x4 ga = {0.f,0.f,0.f,0.f}, gb = {0.f,0.f,0.f,0.f};
        #pragma unroll
        for (int s = 0; s < 4; ++s){
            bf16x8 bv0 = cvtFrag(wp3 + 32 * s);
            bf16x8 bv1 = cvtFrag(wp3 + 32 * (s + 4));
            fa = MFMA16(bv0, aF[s],     fa);
            ga = MFMA16(bv0, aB[s],     ga);
            fb = MFMA16(bv1, aF[s + 4], fb);
            gb = MFMA16(bv1, aB[s + 4], gb);
        }
        int fbase = 4 * q;
        size_t token = tb + c;
        float sp[4], dv[4];
        #pragma unroll
        for (int r = 0; r < 4; ++r){
            int fi   = fbase + r;
            float bn = b3[(fi < KEV) ? fi : (KEV - 1)];
            float z  = (fa[r] + fb[r]) + bn;
            float a  = fabsf(z);
            float e  = __builtin_amdgcn_exp2f(-1.4426950408889634f * a);  // exp(-|z|)
            sp[r] = fmaxf(z, 0.f) + 0.69314718055994531f * __builtin_amdgcn_logf(1.0f + e);
            float sg = __builtin_amdgcn_rcpf(1.0f + e);
            sg = (z >= 0.f) ? sg : 1.0f - sg;                             // sigmoid(z)
            dv[r] = sg * (ga[r] + gb[r]) * (1.0f / 131072.0f);            // /(B*S)
        }
        float* o0 = out + token * KEV + fbase;
        float* o1 = out + (size_t)NTOK * KEV + token * KEV + fbase;
        if (q < 2){
            *(f32x2*)o0       = (f32x2){sp[0], sp[1]};
            *(f32x2*)(o0 + 2) = (f32x2){sp[2], sp[3]};
            *(f32x2*)o1       = (f32x2){dv[0], dv[1]};
            *(f32x2*)(o1 + 2) = (f32x2){dv[2], dv[3]};
        } else if (q == 2){
            *(f32x2*)o0 = (f32x2){sp[0], sp[1]};
            *(f32x2*)o1 = (f32x2){dv[0], dv[1]};
        }
    }
}

extern "C" void kernel_launch(void* const* d_in, const int* in_sizes, int n_in,
                              void* d_out, int out_size, void* d_ws, size_t ws_size,
                              hipStream_t stream){
    const float* hs = (const float*)d_in[0];
    const float* td = (const float*)d_in[1];
    const float* w1 = (const float*)d_in[2];
    const float* b1 = (const float*)d_in[3];
    const float* w2 = (const float*)d_in[4];
    const float* b2 = (const float*)d_in[5];
    const float* wA = (const float*)d_in[6];
    const float* bA = (const float*)d_in[7];
    const float* wB = (const float*)d_in[8];
    const float* bB = (const float*)d_in[9];
    const float* w3 = (const float*)d_in[10];
    const float* b3 = (const float*)d_in[11];

    float*          vc  = (float*)d_ws;                              // 512 fp32
    __hip_bfloat16* wpk = (__hip_bfloat16*)((char*)d_ws + 4096);     // 48*8KB packed weights
    float*          outp = (float*)d_out;

    prep_vc  <<<64, 256, 0, stream>>>(w1, b1, w2, b2, vc);
    prep_pack<<<48, 256, 0, stream>>>(w2, wA, wB, wpk);
    chfn_kernel<<<NTOK / 64, 256, 0, stream>>>(hs, td, wpk, bA, bB, w3, b3, vc, outp);
}